// Round 3
// baseline (111.718 us; speedup 1.0000x reference)
//
#include <hip/hip_runtime.h>

// Problem: B=32, NC=4, H=512, W=512, fp32 in, two fp32 scalars out.
// lseg = mean BCE-with-logits; liou = 1 - mean_b( sum_c IoU(b,c) / present(b) ).
//
// R5 post-mortem: forcing depth-8 load batches (inline asm) changed NOTHING
// (HBM BW flat, bench 55.2->57.1us). TLP at 8 waves/SIMD already saturates
// the load path: real-run aggregate ~6.0 TB/s == measured copy ceiling
// (6.29 TB/s), half served by L3. seg_main is at its pattern's roofline.
// R6: attack the remaining overhead instead — fuse the 3-dispatch chain
// (memset -> seg_main -> seg_final) into memset + ONE kernel. Last-arriving
// block (completion counter + device-scope fences) does the finalization.
// Loads reverted to plain float4 (R4==R5 perf, simpler); log2-folded BCE kept.

#define NB   32
#define NCL  4
constexpr int HW      = 512 * 512;       // 262144 pixels per (b,c) plane
constexpr int GROUPS  = HW / 4;          // 65536 float4-groups per plane
constexpr int THREADS = 256;
constexpr int BLOCKS_PER_BATCH = 64;
constexpr int NBLK    = NB * BLOCKS_PER_BATCH;    // 2048 blocks
constexpr int TPB     = BLOCKS_PER_BATCH * THREADS;  // 16384 threads per batch
constexpr int ITERS   = GROUPS / TPB;             // 4 groups (16 pixels)/thread

__global__ __launch_bounds__(THREADS, 8)   // <=64 VGPR: 8 waves/SIMD
void seg_fused(const float* __restrict__ pred,
               const float* __restrict__ tgt,
               float* __restrict__ bce_part,  // [NB] per-batch BCE partials
               unsigned* __restrict__ counter, // completion counter
               unsigned* __restrict__ pc_g,   // [NB][NCL] pred counts
               unsigned* __restrict__ tc_g,   // [NB][NCL] tgt counts
               unsigned* __restrict__ tp_g,   // [NB][NCL] true positives
               float* __restrict__ out)       // [2] lseg, liou
{
    const int b     = blockIdx.x & (NB - 1);       // one batch per block
    const int chunk = blockIdx.x >> 5;             // 0..BLOCKS_PER_BATCH-1
    const int tib   = chunk * THREADS + threadIdx.x;

    const float* pp[NCL];
    const float* tq[NCL];
    {
        const size_t t0 = (size_t)b * NCL * HW + 4u * (size_t)tib;
#pragma unroll
        for (int c = 0; c < NCL; ++c) {
            pp[c] = pred + t0 + (size_t)c * HW;
            tq[c] = tgt  + t0 + (size_t)c * HW;
        }
    }

    float bce = 0.0f;     // max(p,0) - p*t part
    float l2s = 0.0f;     // sum log2(1 + 2^(-|p|*log2e)); *ln2 once at the end
    // 8-bit fields: per-thread per-class count <= ITERS*4 = 16 < 255
    unsigned pcP = 0u, tcP = 0u, tpP = 0u;

#pragma unroll
    for (int it = 0; it < ITERS; ++it) {
        const size_t soff = (size_t)it * 4u * TPB;
        float4 pv[NCL], tv[NCL];
#pragma unroll
        for (int c = 0; c < NCL; ++c) {
            pv[c] = *reinterpret_cast<const float4*>(pp[c] + soff);
            tv[c] = *reinterpret_cast<const float4*>(tq[c] + soff);
        }
#pragma unroll
        for (int j = 0; j < 4; ++j) {
            float pj[NCL], tj[NCL];
#pragma unroll
            for (int c = 0; c < NCL; ++c) {
                pj[c] = (&pv[c].x)[j];
                tj[c] = (&tv[c].x)[j];
            }
            // first-occurrence argmax (strict >) matches jnp.argmax
            int cp = 0, ct = 0;
            float bp = pj[0], bt = tj[0];
#pragma unroll
            for (int c = 1; c < NCL; ++c) {
                if (pj[c] > bp) { bp = pj[c]; cp = c; }
                if (tj[c] > bt) { bt = tj[c]; ct = c; }
            }
            const unsigned op = 1u << (cp << 3);
            const unsigned ot = 1u << (ct << 3);
            pcP += op;
            tcP += ot;
            tpP += (cp == ct) ? op : 0u;
            // BCE: max(p,0) - p*t + ln2*log2(1 + 2^(-|p|*log2e))
#pragma unroll
            for (int c = 0; c < NCL; ++c) {
                const float p = pj[c];
                bce += fmaxf(p, 0.0f) - p * tj[c];
                l2s += __builtin_amdgcn_logf(
                           1.0f + __builtin_amdgcn_exp2f(
                                      fabsf(p) * -1.44269504f));
            }
        }
    }
    bce += 0.69314718f * l2s;

    // repack 8-bit -> 16-bit fields in u64 for the wave reduction
    // (64-lane sum <= 16*64 = 1024 < 65536, no overflow)
    unsigned long long P = 0ull, T = 0ull, Q = 0ull;
#pragma unroll
    for (int c = 0; c < NCL; ++c) {
        P |= (unsigned long long)((pcP >> (8 * c)) & 0xFFu) << (16 * c);
        T |= (unsigned long long)((tcP >> (8 * c)) & 0xFFu) << (16 * c);
        Q |= (unsigned long long)((tpP >> (8 * c)) & 0xFFu) << (16 * c);
    }
#pragma unroll
    for (int o = 32; o > 0; o >>= 1) {
        bce += __shfl_xor(bce, o);
        P   += __shfl_xor(P, o);
        T   += __shfl_xor(T, o);
        Q   += __shfl_xor(Q, o);
    }

    // block-level reduction: 4 waves -> one set of atomics per block.
    // block sum per field <= 4*1024 = 4096 < 65536: still no overflow.
    __shared__ float              s_bce[THREADS / 64];
    __shared__ unsigned long long sP[THREADS / 64];
    __shared__ unsigned long long sT[THREADS / 64];
    __shared__ unsigned long long sQ[THREADS / 64];
    __shared__ unsigned           s_old;
    const int wid = threadIdx.x >> 6;
    if ((threadIdx.x & 63) == 0) {
        s_bce[wid] = bce; sP[wid] = P; sT[wid] = T; sQ[wid] = Q;
    }
    __syncthreads();
    if (threadIdx.x == 0) {
        float bs = s_bce[0] + s_bce[1] + s_bce[2] + s_bce[3];
        unsigned long long Ps = sP[0] + sP[1] + sP[2] + sP[3];
        unsigned long long Ts = sT[0] + sT[1] + sT[2] + sT[3];
        unsigned long long Qs = sQ[0] + sQ[1] + sQ[2] + sQ[3];
        atomicAdd(&bce_part[b], bs);
#pragma unroll
        for (int c = 0; c < NCL; ++c) {
            atomicAdd(&pc_g[b * NCL + c], (unsigned)((Ps >> (16 * c)) & 0xFFFFu));
            atomicAdd(&tc_g[b * NCL + c], (unsigned)((Ts >> (16 * c)) & 0xFFFFu));
            atomicAdd(&tp_g[b * NCL + c], (unsigned)((Qs >> (16 * c)) & 0xFFFFu));
        }
        __threadfence();                       // publish before signaling
        s_old = atomicAdd(counter, 1u);        // device-scope completion count
    }
    __syncthreads();
    if (s_old != (unsigned)(NBLK - 1)) return;

    // ---- last-arriving block: finalization (replaces seg_final) ----
    __threadfence();   // acquire: see all other blocks' atomics
    const int t = threadIdx.x;
    float val = 0.0f;
    float bs  = 0.0f;
    if (t < NB) {
        bs = bce_part[t];
        float iou = 0.0f;
        int present = 0;
#pragma unroll
        for (int c = 0; c < NCL; ++c) {
            const float Pc = (float)pc_g[t * NCL + c];
            const float Tc = (float)tc_g[t * NCL + c];
            const float Kc = (float)tp_g[t * NCL + c];
            const float den = Pc + Tc - Kc;
            if (den > 0.0f) iou += Kc / den;
            present += (tc_g[t * NCL + c] > 0u);
        }
        val = iou / (float)present;  // present >= 1 (sum_c tgt_cnt = HW)
    }
    if (t < 64) {                    // wave 0 reduces lanes 0..31 (32..63 are 0)
#pragma unroll
        for (int o = 32; o > 0; o >>= 1) {
            val += __shfl_xor(val, o);
            bs  += __shfl_xor(bs, o);
        }
        if (t == 0) {
            out[0] = bs / (float)((size_t)NB * NCL * HW);  // lseg
            out[1] = 1.0f - val / (float)NB;               // liou
        }
    }
}

extern "C" void kernel_launch(void* const* d_in, const int* in_sizes, int n_in,
                              void* d_out, int out_size, void* d_ws, size_t ws_size,
                              hipStream_t stream) {
    const float* pred = (const float*)d_in[0];
    const float* tgt  = (const float*)d_in[1];
    float* out = (float*)d_out;

    // workspace layout:
    //   [0,128):    bce_part[32] (float)
    //   [128,132):  completion counter (unsigned)
    //   [256,...):  3 x 128 uint counters (pc_g, tc_g, tp_g)
    float*    bce_part = (float*)d_ws;
    unsigned* counter  = (unsigned*)((char*)d_ws + 128);
    unsigned* pc_g     = (unsigned*)((char*)d_ws + 256);
    unsigned* tc_g     = pc_g + NB * NCL;
    unsigned* tp_g     = tc_g + NB * NCL;

    hipMemsetAsync(d_ws, 0, 256 + 3 * NB * NCL * sizeof(unsigned), stream);
    seg_fused<<<NBLK, THREADS, 0, stream>>>(pred, tgt, bce_part, counter,
                                            pc_g, tc_g, tp_g, out);
}

// Round 4
// 49.447 us; speedup vs baseline: 2.2594x; 2.2594x over previous
//
#include <hip/hip_runtime.h>

// Problem: B=32, NC=4, H=512, W=512, fp32 in, two fp32 scalars out.
// lseg = mean BCE-with-logits; liou = 1 - mean_b( sum_c IoU(b,c) / present(b) ).
//
// R6 post-mortem: single-kernel fusion via completion counter REGRESSED 2x
// (55->112us). Device-scope __threadfence + atomic on every block's exit =
// cross-XCD L2 publication cost x2048. Reverted.
// R5/R4 takeaway: streaming loop runs at ~6 TB/s aggregate == the measured
// vector-memory ceiling (6.29 TB/s); load-depth games are nulls.
// R7: shave the non-streaming overhead legitimately:
//   - NO memset dispatch, NO atomics: each block writes a unique 32B record
//     (unconditional write needs no init; dispatch boundary provides
//     visibility to seg_final - no fences).
//   - seg_final: 1 block x 1024 threads reduces 2048 records (64KB).
//   - main loop identical to R4 (plain float4 loads) + log2-folded BCE.

#define NB   32
#define NCL  4
constexpr int HW      = 512 * 512;       // 262144 pixels per (b,c) plane
constexpr int GROUPS  = HW / 4;          // 65536 float4-groups per plane
constexpr int THREADS = 256;
constexpr int BLOCKS_PER_BATCH = 64;
constexpr int NBLK    = NB * BLOCKS_PER_BATCH;       // 2048 blocks
constexpr int TPB     = BLOCKS_PER_BATCH * THREADS;  // 16384 threads per batch
constexpr int ITERS   = GROUPS / TPB;                // 4 groups (16 px)/thread

struct Rec {                 // 32 B per block
    float bce;
    unsigned pad;
    unsigned long long P, T, Q;   // 4x16-bit class fields each (block sums <=4096)
};

__global__ __launch_bounds__(THREADS, 8)   // <=64 VGPR: 8 waves/SIMD
void seg_main(const float* __restrict__ pred,
              const float* __restrict__ tgt,
              Rec* __restrict__ recs)      // [NBLK]
{
    const int b     = blockIdx.x & (NB - 1);       // one batch per block
    const int chunk = blockIdx.x >> 5;             // 0..BLOCKS_PER_BATCH-1
    const int tib   = chunk * THREADS + threadIdx.x;

    const float* pp[NCL];
    const float* tq[NCL];
    {
        const size_t t0 = (size_t)b * NCL * HW + 4u * (size_t)tib;
#pragma unroll
        for (int c = 0; c < NCL; ++c) {
            pp[c] = pred + t0 + (size_t)c * HW;
            tq[c] = tgt  + t0 + (size_t)c * HW;
        }
    }

    float bce = 0.0f;     // max(p,0) - p*t part
    float l2s = 0.0f;     // sum log2(1 + 2^(-|p|*log2e)); *ln2 once at the end
    // 8-bit fields: per-thread per-class count <= ITERS*4 = 16 < 255
    unsigned pcP = 0u, tcP = 0u, tpP = 0u;

#pragma unroll
    for (int it = 0; it < ITERS; ++it) {
        const size_t soff = (size_t)it * 4u * TPB;
        float4 pv[NCL], tv[NCL];
#pragma unroll
        for (int c = 0; c < NCL; ++c) {
            pv[c] = *reinterpret_cast<const float4*>(pp[c] + soff);
            tv[c] = *reinterpret_cast<const float4*>(tq[c] + soff);
        }
#pragma unroll
        for (int j = 0; j < 4; ++j) {
            float pj[NCL], tj[NCL];
#pragma unroll
            for (int c = 0; c < NCL; ++c) {
                pj[c] = (&pv[c].x)[j];
                tj[c] = (&tv[c].x)[j];
            }
            // first-occurrence argmax (strict >) matches jnp.argmax
            int cp = 0, ct = 0;
            float bp = pj[0], bt = tj[0];
#pragma unroll
            for (int c = 1; c < NCL; ++c) {
                if (pj[c] > bp) { bp = pj[c]; cp = c; }
                if (tj[c] > bt) { bt = tj[c]; ct = c; }
            }
            const unsigned op = 1u << (cp << 3);
            const unsigned ot = 1u << (ct << 3);
            pcP += op;
            tcP += ot;
            tpP += (cp == ct) ? op : 0u;
            // BCE: max(p,0) - p*t + ln2*log2(1 + 2^(-|p|*log2e))
#pragma unroll
            for (int c = 0; c < NCL; ++c) {
                const float p = pj[c];
                bce += fmaxf(p, 0.0f) - p * tj[c];
                l2s += __builtin_amdgcn_logf(
                           1.0f + __builtin_amdgcn_exp2f(
                                      fabsf(p) * -1.44269504f));
            }
        }
    }
    bce += 0.69314718f * l2s;

    // repack 8-bit -> 16-bit fields in u64 for the wave reduction
    // (64-lane sum <= 16*64 = 1024 < 65536, no overflow)
    unsigned long long P = 0ull, T = 0ull, Q = 0ull;
#pragma unroll
    for (int c = 0; c < NCL; ++c) {
        P |= (unsigned long long)((pcP >> (8 * c)) & 0xFFu) << (16 * c);
        T |= (unsigned long long)((tcP >> (8 * c)) & 0xFFu) << (16 * c);
        Q |= (unsigned long long)((tpP >> (8 * c)) & 0xFFu) << (16 * c);
    }
#pragma unroll
    for (int o = 32; o > 0; o >>= 1) {
        bce += __shfl_xor(bce, o);
        P   += __shfl_xor(P, o);
        T   += __shfl_xor(T, o);
        Q   += __shfl_xor(Q, o);
    }

    // block-level reduction: 4 waves -> one 32B record store per block.
    // block sum per field <= 4*1024 = 4096 < 65536: fits 16-bit fields.
    __shared__ float              s_bce[THREADS / 64];
    __shared__ unsigned long long sP[THREADS / 64];
    __shared__ unsigned long long sT[THREADS / 64];
    __shared__ unsigned long long sQ[THREADS / 64];
    const int wid = threadIdx.x >> 6;
    if ((threadIdx.x & 63) == 0) {
        s_bce[wid] = bce; sP[wid] = P; sT[wid] = T; sQ[wid] = Q;
    }
    __syncthreads();
    if (threadIdx.x == 0) {
        Rec r;
        r.bce = s_bce[0] + s_bce[1] + s_bce[2] + s_bce[3];
        r.pad = 0u;
        r.P   = sP[0] + sP[1] + sP[2] + sP[3];
        r.T   = sT[0] + sT[1] + sT[2] + sT[3];
        r.Q   = sQ[0] + sQ[1] + sQ[2] + sQ[3];
        recs[blockIdx.x] = r;       // unique slot: no atomics, no init needed
    }
}

// Reduce 2048 records. Records for batch b sit at indices b + 32*k, k=0..63.
// 1024 threads = 16 waves; wave w handles batches 2w (lanes 0-31) and
// 2w+1 (lanes 32-63); lane j in its 32-group loads k=j and k=j+32.
__global__ __launch_bounds__(1024)
void seg_final(const Rec* __restrict__ recs, float* __restrict__ out)
{
    const int t    = threadIdx.x;
    const int wave = t >> 6;
    const int lane = t & 63;
    const int sub  = lane >> 5;          // which batch within the wave
    const int j    = lane & 31;          // 0..31
    const int b    = wave * 2 + sub;     // 0..31

    float bce = 0.0f;
    unsigned pc[NCL] = {0,0,0,0}, tc[NCL] = {0,0,0,0}, tp[NCL] = {0,0,0,0};
#pragma unroll
    for (int h = 0; h < 2; ++h) {
        const Rec r = recs[b + 32 * (j + 32 * h)];
        bce += r.bce;
#pragma unroll
        for (int c = 0; c < NCL; ++c) {
            pc[c] += (unsigned)((r.P >> (16 * c)) & 0xFFFFu);
            tc[c] += (unsigned)((r.T >> (16 * c)) & 0xFFFFu);
            tp[c] += (unsigned)((r.Q >> (16 * c)) & 0xFFFFu);
        }
    }
    // reduce within each 32-lane group (offsets < 32 stay inside the group)
#pragma unroll
    for (int o = 16; o > 0; o >>= 1) {
        bce += __shfl_xor(bce, o);
#pragma unroll
        for (int c = 0; c < NCL; ++c) {
            pc[c] += __shfl_xor(pc[c], o);
            tc[c] += __shfl_xor(tc[c], o);
            tp[c] += __shfl_xor(tp[c], o);
        }
    }

    __shared__ float s_val[NB];
    __shared__ float s_bce[NB];
    if (j == 0) {
        float iou = 0.0f;
        int present = 0;
#pragma unroll
        for (int c = 0; c < NCL; ++c) {
            const float Pc = (float)pc[c];
            const float Tc = (float)tc[c];
            const float Kc = (float)tp[c];
            const float den = Pc + Tc - Kc;
            if (den > 0.0f) iou += Kc / den;
            present += (tc[c] > 0u);
        }
        s_val[b] = iou / (float)present;  // present >= 1 (sum_c tgt_cnt = HW)
        s_bce[b] = bce;
    }
    __syncthreads();
    if (t < 64) {
        float v  = (t < NB) ? s_val[t] : 0.0f;
        float bs = (t < NB) ? s_bce[t] : 0.0f;
#pragma unroll
        for (int o = 32; o > 0; o >>= 1) {
            v  += __shfl_xor(v, o);
            bs += __shfl_xor(bs, o);
        }
        if (t == 0) {
            out[0] = bs / (float)((size_t)NB * NCL * HW);  // lseg
            out[1] = 1.0f - v / (float)NB;                 // liou
        }
    }
}

extern "C" void kernel_launch(void* const* d_in, const int* in_sizes, int n_in,
                              void* d_out, int out_size, void* d_ws, size_t ws_size,
                              hipStream_t stream) {
    const float* pred = (const float*)d_in[0];
    const float* tgt  = (const float*)d_in[1];
    float* out = (float*)d_out;

    Rec* recs = (Rec*)d_ws;   // NBLK * 32 B = 64 KiB

    seg_main<<<NBLK, THREADS, 0, stream>>>(pred, tgt, recs);
    seg_final<<<1, 1024, 0, stream>>>(recs, out);
}